// Round 5
// baseline (365.925 us; speedup 1.0000x reference)
//
#include <hip/hip_runtime.h>

#define N_NODES 50000
#define N_EDGES 800000
#define IN_F 128
#define HID 96
#define NCLS 21
#define CAP 64   // max in-degree capacity; Poisson(16) tail => P(exceed) ~ 1e-13
#define NBLK ((N_NODES + 255) / 256)

// ---------------- bucket-CSR build ----------------
__global__ void k_zero_int(int* __restrict__ p, int n) {
  int i = blockIdx.x * blockDim.x + threadIdx.x;
  if (i < n) p[i] = 0;
}

// one pass: histogram + fill. 4 edges/thread for MLP on the atomic chains.
__global__ __launch_bounds__(256) void k_fill_direct(
    const int* __restrict__ src, const int* __restrict__ tgt,
    int* __restrict__ cnt, int* __restrict__ adj) {
  int base = (blockIdx.x * 256 + threadIdx.x) * 4;
  if (base >= N_EDGES) return;
  int4 t4 = *reinterpret_cast<const int4*>(tgt + base);
  int4 s4 = *reinterpret_cast<const int4*>(src + base);
  int p0 = atomicAdd(&cnt[t4.x], 1);
  int p1 = atomicAdd(&cnt[t4.y], 1);
  int p2 = atomicAdd(&cnt[t4.z], 1);
  int p3 = atomicAdd(&cnt[t4.w], 1);
  if (p0 < CAP) adj[(size_t)t4.x * CAP + p0] = s4.x;
  if (p1 < CAP) adj[(size_t)t4.y * CAP + p1] = s4.y;
  if (p2 < CAP) adj[(size_t)t4.z * CAP + p2] = s4.z;
  if (p3 < CAP) adj[(size_t)t4.w * CAP + p3] = s4.w;
}

__global__ void k_dinv_from_cnt(const int* __restrict__ cnt, float* __restrict__ dinv) {
  int i = blockIdx.x * blockDim.x + threadIdx.x;
  if (i < N_NODES) dinv[i] = rsqrtf(1.0f + (float)cnt[i]);  // +1 self-loop
}

// ---------------- register-tiled GEMM: g[n][f] = dinv[n]*(A@W)[n][f] ----------------
template<int K>
__global__ __launch_bounds__(256) void k_gemm_tile(
    const float* __restrict__ A, const float* __restrict__ W,
    const float* __restrict__ dinv, float* __restrict__ g) {
  constexpr int BM = 64, KB = 32;
  __shared__ float As[KB][BM + 4];
  __shared__ float Ws[KB][HID];
  int tid = threadIdx.x;
  int tx = tid & 15;
  int ty = tid >> 4;
  int f0 = tx * 6;
  int nbase = blockIdx.x * BM;
  float acc[4][6] = {};

  for (int k0 = 0; k0 < K; k0 += KB) {
#pragma unroll
    for (int i = 0; i < 2; i++) {
      int l = tid + i * 256;
      int row = l >> 3;
      int col = (l & 7) * 4;
      int n = nbase + row;
      float4 a4 = make_float4(0.f, 0.f, 0.f, 0.f);
      if (n < N_NODES) a4 = *reinterpret_cast<const float4*>(A + (size_t)n * K + k0 + col);
      As[col + 0][row] = a4.x;
      As[col + 1][row] = a4.y;
      As[col + 2][row] = a4.z;
      As[col + 3][row] = a4.w;
    }
#pragma unroll
    for (int i = 0; i < 3; i++) {
      int l = tid + i * 256;
      int row = l / 24;
      int col = (l % 24) * 4;
      *reinterpret_cast<float4*>(&Ws[row][col]) =
          *reinterpret_cast<const float4*>(W + (size_t)(k0 + row) * HID + col);
    }
    __syncthreads();
#pragma unroll
    for (int k = 0; k < KB; k++) {
      float4 a4 = *reinterpret_cast<const float4*>(&As[k][ty * 4]);
      float2 w01 = *reinterpret_cast<const float2*>(&Ws[k][f0]);
      float2 w23 = *reinterpret_cast<const float2*>(&Ws[k][f0 + 2]);
      float2 w45 = *reinterpret_cast<const float2*>(&Ws[k][f0 + 4]);
      float av[4] = {a4.x, a4.y, a4.z, a4.w};
      float wv[6] = {w01.x, w01.y, w23.x, w23.y, w45.x, w45.y};
#pragma unroll
      for (int i = 0; i < 4; i++)
#pragma unroll
        for (int j = 0; j < 6; j++) acc[i][j] += av[i] * wv[j];
    }
    __syncthreads();
  }

#pragma unroll
  for (int i = 0; i < 4; i++) {
    int n = nbase + ty * 4 + i;
    if (n >= N_NODES) break;
    float d = dinv[n];
    float* gp = g + (size_t)n * HID + f0;
#pragma unroll
    for (int j = 0; j < 6; j++) gp[j] = acc[i][j] * d;
  }
}

// ---------------- fused aggregate: h = leaky(dinv*(g[n] + sum_in g[src]) + b) ----------------
// one wave per node; 8-wide predicated unroll (always full iterations, masked FMA)
__global__ __launch_bounds__(256) void k_aggregate(
    const float* __restrict__ g, const int* __restrict__ cnt,
    const int* __restrict__ adj, const float* __restrict__ dinv,
    const float* __restrict__ b, float* __restrict__ h) {
  int wave = threadIdx.x >> 6;
  int lane = threadIdx.x & 63;
  int n = blockIdx.x * 4 + wave;
  if (n >= N_NODES) return;
  bool lo = lane < 32;
  int deg = cnt[n];
  if (deg > CAP) deg = CAP;
  const int* al = adj + (size_t)n * CAP;
  const float* grow = g + (size_t)n * HID;
  float s0 = grow[lane];
  float s1 = lo ? grow[64 + lane] : 0.f;

  for (int j = 0; j < deg; j += 8) {
    float a[8], c[8], m[8];
#pragma unroll
    for (int u = 0; u < 8; u++) {
      bool valid = (j + u) < deg;
      int idx = valid ? al[j + u] : n;
      m[u] = valid ? 1.f : 0.f;
      const float* p = g + (size_t)idx * HID;
      a[u] = p[lane];
      c[u] = lo ? p[64 + lane] : 0.f;
    }
#pragma unroll
    for (int u = 0; u < 8; u++) {
      s0 += m[u] * a[u];
      s1 += m[u] * c[u];
    }
  }

  float d = dinv[n];
  float v0 = d * s0 + b[lane];
  h[(size_t)n * HID + lane] = v0 > 0.f ? v0 : 0.01f * v0;
  if (lo) {
    float v1 = d * s1 + b[64 + lane];
    h[(size_t)n * HID + 64 + lane] = v1 > 0.f ? v1 : 0.01f * v1;
  }
}

// ---------------- final linear: out = H @ Wl + bl ----------------
__global__ __launch_bounds__(256) void k_final(
    const float* __restrict__ H, const float* __restrict__ Wl,
    const float* __restrict__ bl, float* __restrict__ out) {
  __shared__ float w[HID * NCLS];
  __shared__ float bs[NCLS];
  int tid = threadIdx.x;
  for (int i = tid; i < HID * NCLS; i += 256) w[i] = Wl[i];
  if (tid < NCLS) bs[tid] = bl[tid];
  __syncthreads();
  int idx = blockIdx.x * 256 + tid;
  if (idx >= N_NODES * NCLS) return;
  int n = idx / NCLS;
  int c = idx - n * NCLS;
  const float* a = H + (size_t)n * HID;
  float s = bs[c];
#pragma unroll
  for (int k = 0; k < HID; k++) s += a[k] * w[k * NCLS + c];
  out[idx] = s;
}

extern "C" void kernel_launch(void* const* d_in, const int* in_sizes, int n_in,
                              void* d_out, int out_size, void* d_ws, size_t ws_size,
                              hipStream_t stream) {
  const float* x  = (const float*)d_in[0];
  const int* ei   = (const int*)d_in[1];
  const int* src  = ei;             // edge_index[0]
  const int* tgt  = ei + N_EDGES;   // edge_index[1]
  const float* W1 = (const float*)d_in[2];
  const float* b1 = (const float*)d_in[3];
  const float* W2 = (const float*)d_in[4];
  const float* b2 = (const float*)d_in[5];
  const float* W3 = (const float*)d_in[6];
  const float* b3 = (const float*)d_in[7];
  const float* Wl = (const float*)d_in[8];
  const float* bl = (const float*)d_in[9];
  float* out = (float*)d_out;

  // workspace layout (~51.6 MB)
  float* dinv = (float*)d_ws;                          // N
  float* bufA = dinv + N_NODES;                        // N*96
  float* bufB = bufA + (size_t)N_NODES * HID;          // N*96
  int*   cnt  = (int*)(bufB + (size_t)N_NODES * HID);  // N
  int*   adj  = cnt + N_NODES;                         // N*CAP

  // ---- bucket-CSR build (one edge pass; also yields degrees -> dinv) ----
  k_zero_int<<<NBLK, 256, 0, stream>>>(cnt, N_NODES);
  k_fill_direct<<<(N_EDGES / 4 + 255) / 256, 256, 0, stream>>>(src, tgt, cnt, adj);
  k_dinv_from_cnt<<<NBLK, 256, 0, stream>>>(cnt, dinv);

  const int ggrid = (N_NODES + 63) / 64;
  const int agrid = (N_NODES + 3) / 4;

  // ---- layer 1 ----
  k_gemm_tile<IN_F><<<ggrid, 256, 0, stream>>>(x, W1, dinv, bufA);
  k_aggregate<<<agrid, 256, 0, stream>>>(bufA, cnt, adj, dinv, b1, bufB);
  // ---- layer 2 ----
  k_gemm_tile<HID><<<ggrid, 256, 0, stream>>>(bufB, W2, dinv, bufA);
  k_aggregate<<<agrid, 256, 0, stream>>>(bufA, cnt, adj, dinv, b2, bufB);
  // ---- layer 3 ----
  k_gemm_tile<HID><<<ggrid, 256, 0, stream>>>(bufB, W3, dinv, bufA);
  k_aggregate<<<agrid, 256, 0, stream>>>(bufA, cnt, adj, dinv, b3, bufB);

  // ---- classifier ----
  k_final<<<(N_NODES * NCLS + 255) / 256, 256, 0, stream>>>(bufB, Wl, bl, out);
}

// Round 6
// 311.272 us; speedup vs baseline: 1.1756x; 1.1756x over previous
//
#include <hip/hip_runtime.h>

#define N_NODES 50000
#define N_EDGES 800000
#define IN_F 128
#define HID 96
#define NCLS 21
#define CAP 64   // max in-degree capacity; Poisson(16) tail => P(exceed) ~ 1e-13
#define NBLK ((N_NODES + 255) / 256)

// ---------------- bucket-CSR build ----------------
__global__ void k_zero_int(int* __restrict__ p, int n) {
  int i = blockIdx.x * blockDim.x + threadIdx.x;
  if (i < n) p[i] = 0;
}

// one pass: histogram + fill. 4 edges/thread for MLP on the atomic chains.
__global__ __launch_bounds__(256) void k_fill_direct(
    const int* __restrict__ src, const int* __restrict__ tgt,
    int* __restrict__ cnt, int* __restrict__ adj) {
  int base = (blockIdx.x * 256 + threadIdx.x) * 4;
  if (base >= N_EDGES) return;
  int4 t4 = *reinterpret_cast<const int4*>(tgt + base);
  int4 s4 = *reinterpret_cast<const int4*>(src + base);
  int p0 = atomicAdd(&cnt[t4.x], 1);
  int p1 = atomicAdd(&cnt[t4.y], 1);
  int p2 = atomicAdd(&cnt[t4.z], 1);
  int p3 = atomicAdd(&cnt[t4.w], 1);
  if (p0 < CAP) adj[(size_t)t4.x * CAP + p0] = s4.x;
  if (p1 < CAP) adj[(size_t)t4.y * CAP + p1] = s4.y;
  if (p2 < CAP) adj[(size_t)t4.z * CAP + p2] = s4.z;
  if (p3 < CAP) adj[(size_t)t4.w * CAP + p3] = s4.w;
}

__global__ void k_dinv_from_cnt(const int* __restrict__ cnt, float* __restrict__ dinv) {
  int i = blockIdx.x * blockDim.x + threadIdx.x;
  if (i < N_NODES) dinv[i] = rsqrtf(1.0f + (float)cnt[i]);  // +1 self-loop
}

// ---------------- register-tiled GEMM: g[n][f] = dinv[n]*(A@W)[n][f] ----------------
template<int K>
__global__ __launch_bounds__(256) void k_gemm_tile(
    const float* __restrict__ A, const float* __restrict__ W,
    const float* __restrict__ dinv, float* __restrict__ g) {
  constexpr int BM = 64, KB = 32;
  __shared__ float As[KB][BM + 4];
  __shared__ float Ws[KB][HID];
  int tid = threadIdx.x;
  int tx = tid & 15;
  int ty = tid >> 4;
  int f0 = tx * 6;
  int nbase = blockIdx.x * BM;
  float acc[4][6] = {};

  for (int k0 = 0; k0 < K; k0 += KB) {
#pragma unroll
    for (int i = 0; i < 2; i++) {
      int l = tid + i * 256;
      int row = l >> 3;
      int col = (l & 7) * 4;
      int n = nbase + row;
      float4 a4 = make_float4(0.f, 0.f, 0.f, 0.f);
      if (n < N_NODES) a4 = *reinterpret_cast<const float4*>(A + (size_t)n * K + k0 + col);
      As[col + 0][row] = a4.x;
      As[col + 1][row] = a4.y;
      As[col + 2][row] = a4.z;
      As[col + 3][row] = a4.w;
    }
#pragma unroll
    for (int i = 0; i < 3; i++) {
      int l = tid + i * 256;
      int row = l / 24;
      int col = (l % 24) * 4;
      *reinterpret_cast<float4*>(&Ws[row][col]) =
          *reinterpret_cast<const float4*>(W + (size_t)(k0 + row) * HID + col);
    }
    __syncthreads();
#pragma unroll
    for (int k = 0; k < KB; k++) {
      float4 a4 = *reinterpret_cast<const float4*>(&As[k][ty * 4]);
      float2 w01 = *reinterpret_cast<const float2*>(&Ws[k][f0]);
      float2 w23 = *reinterpret_cast<const float2*>(&Ws[k][f0 + 2]);
      float2 w45 = *reinterpret_cast<const float2*>(&Ws[k][f0 + 4]);
      float av[4] = {a4.x, a4.y, a4.z, a4.w};
      float wv[6] = {w01.x, w01.y, w23.x, w23.y, w45.x, w45.y};
#pragma unroll
      for (int i = 0; i < 4; i++)
#pragma unroll
        for (int j = 0; j < 6; j++) acc[i][j] += av[i] * wv[j];
    }
    __syncthreads();
  }

#pragma unroll
  for (int i = 0; i < 4; i++) {
    int n = nbase + ty * 4 + i;
    if (n >= N_NODES) break;
    float d = dinv[n];
    float* gp = g + (size_t)n * HID + f0;
#pragma unroll
    for (int j = 0; j < 6; j++) gp[j] = acc[i][j] * d;
  }
}

// ---------------- fused aggregate: h = leaky(dinv*(g[n] + sum_in g[src]) + b) ----------------
// one wave per node; adjacency bucket loaded into one register (coalesced),
// indices broadcast via __shfl; 8-wide exact-trip unroll, then 4-wide, then scalar.
__global__ __launch_bounds__(256) void k_aggregate(
    const float* __restrict__ g, const int* __restrict__ cnt,
    const int* __restrict__ adj, const float* __restrict__ dinv,
    const float* __restrict__ b, float* __restrict__ h) {
  int wave = threadIdx.x >> 6;
  int lane = threadIdx.x & 63;
  int n = blockIdx.x * 4 + wave;
  if (n >= N_NODES) return;
  bool lo = lane < 32;
  int deg = cnt[n];
  if (deg > CAP) deg = CAP;
  const int* al = adj + (size_t)n * CAP;
  int myidx = (lane < deg) ? al[lane] : 0;   // whole bucket in one coalesced load

  const float* grow = g + (size_t)n * HID;
  float s0 = grow[lane];
  float s1 = lo ? grow[64 + lane] : 0.f;

  int j = 0;
  for (; j + 8 <= deg; j += 8) {
    const float* p[8];
#pragma unroll
    for (int u = 0; u < 8; u++) p[u] = g + (size_t)__shfl(myidx, j + u) * HID;
    float a[8], c[8];
#pragma unroll
    for (int u = 0; u < 8; u++) a[u] = p[u][lane];
#pragma unroll
    for (int u = 0; u < 8; u++) c[u] = lo ? p[u][64 + lane] : 0.f;
#pragma unroll
    for (int u = 0; u < 8; u++) { s0 += a[u]; s1 += c[u]; }
  }
  if (j + 4 <= deg) {
    const float* p[4];
#pragma unroll
    for (int u = 0; u < 4; u++) p[u] = g + (size_t)__shfl(myidx, j + u) * HID;
    float a[4], c[4];
#pragma unroll
    for (int u = 0; u < 4; u++) a[u] = p[u][lane];
#pragma unroll
    for (int u = 0; u < 4; u++) c[u] = lo ? p[u][64 + lane] : 0.f;
#pragma unroll
    for (int u = 0; u < 4; u++) { s0 += a[u]; s1 += c[u]; }
    j += 4;
  }
  for (; j < deg; j++) {
    const float* p = g + (size_t)__shfl(myidx, j) * HID;
    s0 += p[lane];
    if (lo) s1 += p[64 + lane];
  }

  float d = dinv[n];
  float v0 = d * s0 + b[lane];
  h[(size_t)n * HID + lane] = v0 > 0.f ? v0 : 0.01f * v0;
  if (lo) {
    float v1 = d * s1 + b[64 + lane];
    h[(size_t)n * HID + 64 + lane] = v1 > 0.f ? v1 : 0.01f * v1;
  }
}

// ---------------- final linear: out = H @ Wl + bl ----------------
__global__ __launch_bounds__(256) void k_final(
    const float* __restrict__ H, const float* __restrict__ Wl,
    const float* __restrict__ bl, float* __restrict__ out) {
  __shared__ float w[HID * NCLS];
  __shared__ float bs[NCLS];
  int tid = threadIdx.x;
  for (int i = tid; i < HID * NCLS; i += 256) w[i] = Wl[i];
  if (tid < NCLS) bs[tid] = bl[tid];
  __syncthreads();
  int idx = blockIdx.x * 256 + tid;
  if (idx >= N_NODES * NCLS) return;
  int n = idx / NCLS;
  int c = idx - n * NCLS;
  const float* a = H + (size_t)n * HID;
  float s = bs[c];
#pragma unroll
  for (int k = 0; k < HID; k++) s += a[k] * w[k * NCLS + c];
  out[idx] = s;
}

extern "C" void kernel_launch(void* const* d_in, const int* in_sizes, int n_in,
                              void* d_out, int out_size, void* d_ws, size_t ws_size,
                              hipStream_t stream) {
  const float* x  = (const float*)d_in[0];
  const int* ei   = (const int*)d_in[1];
  const int* src  = ei;             // edge_index[0]
  const int* tgt  = ei + N_EDGES;   // edge_index[1]
  const float* W1 = (const float*)d_in[2];
  const float* b1 = (const float*)d_in[3];
  const float* W2 = (const float*)d_in[4];
  const float* b2 = (const float*)d_in[5];
  const float* W3 = (const float*)d_in[6];
  const float* b3 = (const float*)d_in[7];
  const float* Wl = (const float*)d_in[8];
  const float* bl = (const float*)d_in[9];
  float* out = (float*)d_out;

  // workspace layout (~51.6 MB)
  float* dinv = (float*)d_ws;                          // N
  float* bufA = dinv + N_NODES;                        // N*96
  float* bufB = bufA + (size_t)N_NODES * HID;          // N*96
  int*   cnt  = (int*)(bufB + (size_t)N_NODES * HID);  // N
  int*   adj  = cnt + N_NODES;                         // N*CAP

  // ---- bucket-CSR build (one edge pass; also yields degrees -> dinv) ----
  k_zero_int<<<NBLK, 256, 0, stream>>>(cnt, N_NODES);
  k_fill_direct<<<(N_EDGES / 4 + 255) / 256, 256, 0, stream>>>(src, tgt, cnt, adj);
  k_dinv_from_cnt<<<NBLK, 256, 0, stream>>>(cnt, dinv);

  const int ggrid = (N_NODES + 63) / 64;
  const int agrid = (N_NODES + 3) / 4;

  // ---- layer 1 ----
  k_gemm_tile<IN_F><<<ggrid, 256, 0, stream>>>(x, W1, dinv, bufA);
  k_aggregate<<<agrid, 256, 0, stream>>>(bufA, cnt, adj, dinv, b1, bufB);
  // ---- layer 2 ----
  k_gemm_tile<HID><<<ggrid, 256, 0, stream>>>(bufB, W2, dinv, bufA);
  k_aggregate<<<agrid, 256, 0, stream>>>(bufA, cnt, adj, dinv, b2, bufB);
  // ---- layer 3 ----
  k_gemm_tile<HID><<<ggrid, 256, 0, stream>>>(bufB, W3, dinv, bufA);
  k_aggregate<<<agrid, 256, 0, stream>>>(bufA, cnt, adj, dinv, b3, bufB);

  // ---- classifier ----
  k_final<<<(N_NODES * NCLS + 255) / 256, 256, 0, stream>>>(bufB, Wl, bl, out);
}

// Round 7
// 278.809 us; speedup vs baseline: 1.3125x; 1.1164x over previous
//
#include <hip/hip_runtime.h>

#define N_NODES 50000
#define N_EDGES 800000
#define IN_F 128
#define HID 96
#define NCLS 21
#define NBUCK 196        // coarse bucket = tgt>>8  (49999>>8 = 195)
#define BCAP  4608       // per-bucket capacity: mean 4082, +8 sigma
#define CPAD  16         // cursor stride in ints -> one 64B line per counter

// ---------------- zero ----------------
__global__ void k_zero_int(int* __restrict__ p, int n) {
  int i = blockIdx.x * blockDim.x + threadIdx.x;
  if (i < n) p[i] = 0;
}

// ---------------- pass 1: bin edges by tgt>>8 (dense-in-time writes) ----------------
__global__ __launch_bounds__(1024) void k_bin(
    const int* __restrict__ src, const int* __restrict__ tgt,
    int* __restrict__ cursor, int* __restrict__ packed) {
  __shared__ int lhist[NBUCK];
  __shared__ int gbase[NBUCK];
  int tid = threadIdx.x;
  if (tid < NBUCK) lhist[tid] = 0;
  __syncthreads();
  int me = blockIdx.x * 4096 + tid * 4;
  int4 t4, s4;
  int b0 = 0, b1 = 0, b2 = 0, b3 = 0;
  bool valid = me < N_EDGES;
  if (valid) {
    t4 = *reinterpret_cast<const int4*>(tgt + me);
    s4 = *reinterpret_cast<const int4*>(src + me);
    b0 = t4.x >> 8; b1 = t4.y >> 8; b2 = t4.z >> 8; b3 = t4.w >> 8;
    atomicAdd(&lhist[b0], 1); atomicAdd(&lhist[b1], 1);
    atomicAdd(&lhist[b2], 1); atomicAdd(&lhist[b3], 1);
  }
  __syncthreads();
  if (tid < NBUCK) {
    int c = lhist[tid];
    gbase[tid] = c ? atomicAdd(&cursor[tid * CPAD], c) : 0;
    lhist[tid] = 0;
  }
  __syncthreads();
  if (valid) {
    int r, pos;
    r = atomicAdd(&lhist[b0], 1);
    pos = gbase[b0] + r;
    if (pos < BCAP) packed[b0 * BCAP + pos] = (s4.x << 8) | (t4.x & 255);
    r = atomicAdd(&lhist[b1], 1);
    pos = gbase[b1] + r;
    if (pos < BCAP) packed[b1 * BCAP + pos] = (s4.y << 8) | (t4.y & 255);
    r = atomicAdd(&lhist[b2], 1);
    pos = gbase[b2] + r;
    if (pos < BCAP) packed[b2 * BCAP + pos] = (s4.z << 8) | (t4.z & 255);
    r = atomicAdd(&lhist[b3], 1);
    pos = gbase[b3] + r;
    if (pos < BCAP) packed[b3 * BCAP + pos] = (s4.w << 8) | (t4.w & 255);
  }
}

// ---------------- pass 2: per-bucket LDS counting sort -> CSR + deg + dinv ----------------
__global__ __launch_bounds__(256) void k_build(
    const int* __restrict__ cursor, const int* __restrict__ packed,
    int* __restrict__ adj, int* __restrict__ degarr,
    int* __restrict__ rowptr, float* __restrict__ dinv) {
  __shared__ int ncnt[256];
  __shared__ int noff[256];
  __shared__ int nrank[256];
  __shared__ int ws[4];
  int b = blockIdx.x;
  int tid = threadIdx.x;
  int cntb = cursor[b * CPAD];
  if (cntb > BCAP) cntb = BCAP;
  ncnt[tid] = 0;
  nrank[tid] = 0;
  __syncthreads();
  const int* pk = packed + b * BCAP;
  for (int i = tid; i < cntb; i += 256) atomicAdd(&ncnt[pk[i] & 255], 1);
  __syncthreads();
  // exclusive scan of ncnt -> noff
  {
    int lane = tid & 63, wid = tid >> 6;
    int v = ncnt[tid];
    int x = v;
#pragma unroll
    for (int off = 1; off < 64; off <<= 1) {
      int y = __shfl_up(x, off);
      if (lane >= off) x += y;
    }
    if (lane == 63) ws[wid] = x;
    __syncthreads();
    if (tid == 0) {
      int t0 = ws[0], t1 = ws[1], t2 = ws[2];
      ws[3] = t0 + t1 + t2; ws[2] = t0 + t1; ws[1] = t0; ws[0] = 0;
    }
    __syncthreads();
    noff[tid] = ws[wid] + x - v;
  }
  __syncthreads();
  int n = (b << 8) + tid;
  if (n < N_NODES) {
    int d = ncnt[tid];
    degarr[n] = d;
    rowptr[n] = b * BCAP + noff[tid];
    dinv[n] = rsqrtf(1.0f + (float)d);  // +1 self-loop
  }
  __syncthreads();
  for (int i = tid; i < cntb; i += 256) {
    int e = pk[i];
    int low = e & 255;
    int r = atomicAdd(&nrank[low], 1);
    adj[b * BCAP + noff[low] + r] = e >> 8;
  }
}

// ---------------- register-tiled GEMM: g[n][f] = dinv[n]*(A@W)[n][f] ----------------
template<int K>
__global__ __launch_bounds__(256) void k_gemm_tile(
    const float* __restrict__ A, const float* __restrict__ W,
    const float* __restrict__ dinv, float* __restrict__ g) {
  constexpr int BM = 64, KB = 32;
  __shared__ float As[KB][BM + 4];
  __shared__ float Ws[KB][HID];
  int tid = threadIdx.x;
  int tx = tid & 15;
  int ty = tid >> 4;
  int f0 = tx * 6;
  int nbase = blockIdx.x * BM;
  float acc[4][6] = {};

  for (int k0 = 0; k0 < K; k0 += KB) {
#pragma unroll
    for (int i = 0; i < 2; i++) {
      int l = tid + i * 256;
      int row = l >> 3;
      int col = (l & 7) * 4;
      int n = nbase + row;
      float4 a4 = make_float4(0.f, 0.f, 0.f, 0.f);
      if (n < N_NODES) a4 = *reinterpret_cast<const float4*>(A + (size_t)n * K + k0 + col);
      As[col + 0][row] = a4.x;
      As[col + 1][row] = a4.y;
      As[col + 2][row] = a4.z;
      As[col + 3][row] = a4.w;
    }
#pragma unroll
    for (int i = 0; i < 3; i++) {
      int l = tid + i * 256;
      int row = l / 24;
      int col = (l % 24) * 4;
      *reinterpret_cast<float4*>(&Ws[row][col]) =
          *reinterpret_cast<const float4*>(W + (size_t)(k0 + row) * HID + col);
    }
    __syncthreads();
#pragma unroll
    for (int k = 0; k < KB; k++) {
      float4 a4 = *reinterpret_cast<const float4*>(&As[k][ty * 4]);
      float2 w01 = *reinterpret_cast<const float2*>(&Ws[k][f0]);
      float2 w23 = *reinterpret_cast<const float2*>(&Ws[k][f0 + 2]);
      float2 w45 = *reinterpret_cast<const float2*>(&Ws[k][f0 + 4]);
      float av[4] = {a4.x, a4.y, a4.z, a4.w};
      float wv[6] = {w01.x, w01.y, w23.x, w23.y, w45.x, w45.y};
#pragma unroll
      for (int i = 0; i < 4; i++)
#pragma unroll
        for (int j = 0; j < 6; j++) acc[i][j] += av[i] * wv[j];
    }
    __syncthreads();
  }

#pragma unroll
  for (int i = 0; i < 4; i++) {
    int n = nbase + ty * 4 + i;
    if (n >= N_NODES) break;
    float d = dinv[n];
    float* gp = g + (size_t)n * HID + f0;
#pragma unroll
    for (int j = 0; j < 6; j++) gp[j] = acc[i][j] * d;
  }
}

// ---------------- fused aggregate: h = leaky(dinv*(g[n] + sum_in g[src]) + b) ----------------
// one wave per node; adjacency row in a lane register, indices via __shfl;
// 16/8/4/1 exact-trip unroll for deep load pipelining.
__global__ __launch_bounds__(256) void k_aggregate(
    const float* __restrict__ g, const int* __restrict__ degarr,
    const int* __restrict__ rowptr, const int* __restrict__ adj,
    const float* __restrict__ dinv, const float* __restrict__ b,
    float* __restrict__ h) {
  int wave = threadIdx.x >> 6;
  int lane = threadIdx.x & 63;
  int n = blockIdx.x * 4 + wave;
  if (n >= N_NODES) return;
  bool lo = lane < 32;
  int deg = degarr[n];
  const int* al = adj + rowptr[n];
  int myidx = (lane < deg) ? al[lane] : 0;   // coalesced row load

  const float* grow = g + (size_t)n * HID;
  float s0 = grow[lane];
  float s1 = lo ? grow[64 + lane] : 0.f;

  int dd = deg > 64 ? 64 : deg;
  int j = 0;
  for (; j + 16 <= dd; j += 16) {
    const float* p[16];
#pragma unroll
    for (int u = 0; u < 16; u++) p[u] = g + (size_t)__shfl(myidx, j + u) * HID;
    float a[16], c[16];
#pragma unroll
    for (int u = 0; u < 16; u++) a[u] = p[u][lane];
#pragma unroll
    for (int u = 0; u < 16; u++) c[u] = lo ? p[u][64 + lane] : 0.f;
#pragma unroll
    for (int u = 0; u < 16; u++) { s0 += a[u]; s1 += c[u]; }
  }
  if (j + 8 <= dd) {
    const float* p[8];
#pragma unroll
    for (int u = 0; u < 8; u++) p[u] = g + (size_t)__shfl(myidx, j + u) * HID;
    float a[8], c[8];
#pragma unroll
    for (int u = 0; u < 8; u++) a[u] = p[u][lane];
#pragma unroll
    for (int u = 0; u < 8; u++) c[u] = lo ? p[u][64 + lane] : 0.f;
#pragma unroll
    for (int u = 0; u < 8; u++) { s0 += a[u]; s1 += c[u]; }
    j += 8;
  }
  if (j + 4 <= dd) {
    const float* p[4];
#pragma unroll
    for (int u = 0; u < 4; u++) p[u] = g + (size_t)__shfl(myidx, j + u) * HID;
    float a[4], c[4];
#pragma unroll
    for (int u = 0; u < 4; u++) a[u] = p[u][lane];
#pragma unroll
    for (int u = 0; u < 4; u++) c[u] = lo ? p[u][64 + lane] : 0.f;
#pragma unroll
    for (int u = 0; u < 4; u++) { s0 += a[u]; s1 += c[u]; }
    j += 4;
  }
  for (; j < dd; j++) {
    const float* p = g + (size_t)__shfl(myidx, j) * HID;
    s0 += p[lane];
    if (lo) s1 += p[64 + lane];
  }
  for (; j < deg; j++) {  // deg > 64: essentially impossible, but correct
    const float* p = g + (size_t)al[j] * HID;
    s0 += p[lane];
    if (lo) s1 += p[64 + lane];
  }

  float d = dinv[n];
  float v0 = d * s0 + b[lane];
  h[(size_t)n * HID + lane] = v0 > 0.f ? v0 : 0.01f * v0;
  if (lo) {
    float v1 = d * s1 + b[64 + lane];
    h[(size_t)n * HID + 64 + lane] = v1 > 0.f ? v1 : 0.01f * v1;
  }
}

// ---------------- final linear: out = H @ Wl + bl ----------------
__global__ __launch_bounds__(256) void k_final(
    const float* __restrict__ H, const float* __restrict__ Wl,
    const float* __restrict__ bl, float* __restrict__ out) {
  __shared__ float w[HID * NCLS];
  __shared__ float bs[NCLS];
  int tid = threadIdx.x;
  for (int i = tid; i < HID * NCLS; i += 256) w[i] = Wl[i];
  if (tid < NCLS) bs[tid] = bl[tid];
  __syncthreads();
  int idx = blockIdx.x * 256 + tid;
  if (idx >= N_NODES * NCLS) return;
  int n = idx / NCLS;
  int c = idx - n * NCLS;
  const float* a = H + (size_t)n * HID;
  float s = bs[c];
#pragma unroll
  for (int k = 0; k < HID; k++) s += a[k] * w[k * NCLS + c];
  out[idx] = s;
}

extern "C" void kernel_launch(void* const* d_in, const int* in_sizes, int n_in,
                              void* d_out, int out_size, void* d_ws, size_t ws_size,
                              hipStream_t stream) {
  const float* x  = (const float*)d_in[0];
  const int* ei   = (const int*)d_in[1];
  const int* src  = ei;             // edge_index[0]
  const int* tgt  = ei + N_EDGES;   // edge_index[1]
  const float* W1 = (const float*)d_in[2];
  const float* b1 = (const float*)d_in[3];
  const float* W2 = (const float*)d_in[4];
  const float* b2 = (const float*)d_in[5];
  const float* W3 = (const float*)d_in[6];
  const float* b3 = (const float*)d_in[7];
  const float* Wl = (const float*)d_in[8];
  const float* bl = (const float*)d_in[9];
  float* out = (float*)d_out;

  // workspace layout (~46.6 MB)
  float* dinv   = (float*)d_ws;                            // N
  float* bufA   = dinv + N_NODES;                          // N*96
  float* bufB   = bufA + (size_t)N_NODES * HID;            // N*96
  int*   degarr = (int*)(bufB + (size_t)N_NODES * HID);    // N
  int*   rowptr = degarr + N_NODES;                        // N
  int*   cursor = rowptr + N_NODES;                        // NBUCK*CPAD
  int*   packed = cursor + NBUCK * CPAD;                   // NBUCK*BCAP
  int*   adj    = packed + NBUCK * BCAP;                   // NBUCK*BCAP

  // ---- CSR build via 2-level counting sort ----
  k_zero_int<<<(NBUCK * CPAD + 255) / 256, 256, 0, stream>>>(cursor, NBUCK * CPAD);
  k_bin<<<(N_EDGES + 4095) / 4096, 1024, 0, stream>>>(src, tgt, cursor, packed);
  k_build<<<NBUCK, 256, 0, stream>>>(cursor, packed, adj, degarr, rowptr, dinv);

  const int ggrid = (N_NODES + 63) / 64;
  const int agrid = (N_NODES + 3) / 4;

  // ---- layer 1 ----
  k_gemm_tile<IN_F><<<ggrid, 256, 0, stream>>>(x, W1, dinv, bufA);
  k_aggregate<<<agrid, 256, 0, stream>>>(bufA, degarr, rowptr, adj, dinv, b1, bufB);
  // ---- layer 2 ----
  k_gemm_tile<HID><<<ggrid, 256, 0, stream>>>(bufB, W2, dinv, bufA);
  k_aggregate<<<agrid, 256, 0, stream>>>(bufA, degarr, rowptr, adj, dinv, b2, bufB);
  // ---- layer 3 ----
  k_gemm_tile<HID><<<ggrid, 256, 0, stream>>>(bufB, W3, dinv, bufA);
  k_aggregate<<<agrid, 256, 0, stream>>>(bufA, degarr, rowptr, adj, dinv, b3, bufB);

  // ---- classifier ----
  k_final<<<(N_NODES * NCLS + 255) / 256, 256, 0, stream>>>(bufB, Wl, bl, out);
}